// Round 5
// baseline (643.957 us; speedup 1.0000x reference)
//
#include <hip/hip_runtime.h>
#include <cstdint>

typedef unsigned short u16;
typedef unsigned int   u32;
typedef unsigned long long u64;

#define G_ROWS 20000
#define G_PAD  20096      // 157 * 128
#define T_DIM  1536
#define D_DIM  512
#define B_DIM  256
#define TOPK   32
#define SIM_SCALE 0.04419417382415922f   // 1/sqrt(512), screening only
#define SQRT_D    22.62741699796952f     // f32(math.sqrt(512)) — np divides by this
#define BOUND_EPS 2.0e-4f                // screen-vs-np noise is ~5e-6; 40x margin

typedef __bf16 bf16x8 __attribute__((ext_vector_type(8)));
typedef float  f32x4  __attribute__((ext_vector_type(4)));

__device__ __forceinline__ u16 f2bf(float f) {
  u32 u = __float_as_uint(f);
  u += 0x7fffu + ((u >> 16) & 1u);   // RNE
  return (u16)(u >> 16);
}
__device__ __forceinline__ float bf2f(u16 h) {
  return __uint_as_float(((u32)h) << 16);
}
__device__ __forceinline__ u32 fkey(float v) {   // order-preserving f32 -> u32
  u32 b = __float_as_uint(v);
  return (b & 0x80000000u) ? ~b : (b | 0x80000000u);
}

// ---------------- split-conversion: f32 -> (bf16 hi, bf16 lo) ----------------
__global__ __launch_bounds__(256) void conv_split(const float* __restrict__ src,
                                                  u16* __restrict__ hi, u16* __restrict__ lo,
                                                  int valid_rows)
{
  size_t i = ((size_t)blockIdx.x * 256 + threadIdx.x) * 4;
  int row = (int)(i >> 9);
  float4 a = make_float4(0.f, 0.f, 0.f, 0.f);
  if (row < valid_rows) a = *(const float4*)(src + i);
  float v[4] = {a.x, a.y, a.z, a.w};
  u16 h[4], l[4];
#pragma unroll
  for (int c = 0; c < 4; ++c) {
    h[c] = f2bf(v[c]);
    l[c] = f2bf(v[c] - bf2f(h[c]));
  }
  *(uint2*)(hi + i) = make_uint2((u32)h[0] | ((u32)h[1] << 16), (u32)h[2] | ((u32)h[3] << 16));
  *(uint2*)(lo + i) = make_uint2((u32)l[0] | ((u32)l[1] << 16), (u32)l[2] | ((u32)l[3] << 16));
}

// ---------------- tf_expr [B,T] -> tfT [T,B] ----------------
__global__ __launch_bounds__(256) void transpose_tf(const float* __restrict__ in, float* __restrict__ out)
{
  __shared__ float tile[32][33];
  int x = threadIdx.x, y = threadIdx.y;
  int bt = blockIdx.x * 32;
  int bb = blockIdx.y * 32;
#pragma unroll
  for (int i = 0; i < 32; i += 8) tile[y + i][x] = in[(size_t)(bb + y + i) * T_DIM + bt + x];
  __syncthreads();
#pragma unroll
  for (int i = 0; i < 32; i += 8) out[(size_t)(bt + y + i) * B_DIM + bb + x] = tile[x][y + i];
}

// ---------------- async global -> LDS, 16B/lane ----------------
__device__ __forceinline__ void gl16(const u16* g, u16* l) {
  __builtin_amdgcn_global_load_lds((__attribute__((address_space(1))) void*)(void*)g,
                                   (__attribute__((address_space(3))) void*)l, 16, 0, 0);
}

// ---------------- screening GEMM + fused mask: Sim = masked((Ah+Al)(Bh+Bl)^T) ----------------
__global__ __launch_bounds__(256) void gemm_split(const u16* __restrict__ Ah, const u16* __restrict__ Al,
                                                  const u16* __restrict__ Bh, const u16* __restrict__ Bl,
                                                  const int* __restrict__ mask,
                                                  float* __restrict__ Sim)
{
  __shared__ u16 sm[16384];
  const int tid  = threadIdx.x;
  const int lane = tid & 63;
  const int wv   = tid >> 6;
  const int m0 = blockIdx.y * 128;
  const int n0 = blockIdx.x * 128;

  const int erow0 = m0 + ((wv >> 1) << 6) + ((lane >> 4) << 2);
  const int ecol0 = n0 + ((wv & 1) << 6) + (lane & 15);

  // pre-load this lane's 64 mask bits; latency hides under the K-loop
  u64 mbits = 0;
#pragma unroll
  for (int mi = 0; mi < 4; ++mi)
#pragma unroll
    for (int r = 0; r < 4; ++r) {
      int row = erow0 + mi * 16 + r;
      if (row < G_ROWS) {
#pragma unroll
        for (int ni = 0; ni < 4; ++ni) {
          int mk = mask[(size_t)row * T_DIM + ecol0 + ni * 16];
          mbits |= ((u64)(mk != 0)) << ((mi * 4 + r) * 4 + ni);
        }
      }
    }

  f32x4 zero4 = {0.f, 0.f, 0.f, 0.f};
  f32x4 acc[4][4];
#pragma unroll
  for (int i = 0; i < 4; ++i)
#pragma unroll
    for (int j = 0; j < 4; ++j) acc[i][j] = zero4;

  const int r0 = (wv << 4) + (lane >> 2);
  const int c0 = (lane & 3) << 3;
  const size_t aoff = (size_t)(m0 + r0) * 512 + c0;
  const size_t boff = (size_t)(n0 + r0) * 512 + c0;
  u16* lw = sm + (wv << 9);

  const int arow = ((wv >> 1) << 6) + (lane & 15);
  const int brow = ((wv & 1) << 6) + (lane & 15);
  const int kf   = (lane >> 4) << 3;

  for (int kt = 0; kt < 16; ++kt) {
    const int k0 = kt << 5;
    __syncthreads();
    gl16(Ah + aoff + k0,            lw);
    gl16(Ah + aoff + k0 + 64 * 512, lw + 2048);
    gl16(Al + aoff + k0,            lw + 4096);
    gl16(Al + aoff + k0 + 64 * 512, lw + 6144);
    gl16(Bh + boff + k0,            lw + 8192);
    gl16(Bh + boff + k0 + 64 * 512, lw + 10240);
    gl16(Bl + boff + k0,            lw + 12288);
    gl16(Bl + boff + k0 + 64 * 512, lw + 14336);
    __syncthreads();

    bf16x8 aH[4], aL[4], bH[4], bL[4];
#pragma unroll
    for (int mi = 0; mi < 4; ++mi) {
      aH[mi] = *(const bf16x8*)(sm +        (arow + mi * 16) * 32 + kf);
      aL[mi] = *(const bf16x8*)(sm + 4096 + (arow + mi * 16) * 32 + kf);
    }
#pragma unroll
    for (int ni = 0; ni < 4; ++ni) {
      bH[ni] = *(const bf16x8*)(sm + 8192  + (brow + ni * 16) * 32 + kf);
      bL[ni] = *(const bf16x8*)(sm + 12288 + (brow + ni * 16) * 32 + kf);
    }
#pragma unroll
    for (int mi = 0; mi < 4; ++mi)
#pragma unroll
      for (int ni = 0; ni < 4; ++ni) {
        acc[mi][ni] = __builtin_amdgcn_mfma_f32_16x16x32_bf16(aH[mi], bH[ni], acc[mi][ni], 0, 0, 0);
        acc[mi][ni] = __builtin_amdgcn_mfma_f32_16x16x32_bf16(aH[mi], bL[ni], acc[mi][ni], 0, 0, 0);
        acc[mi][ni] = __builtin_amdgcn_mfma_f32_16x16x32_bf16(aL[mi], bH[ni], acc[mi][ni], 0, 0, 0);
      }
  }

  // epilogue: C/D layout col=lane&15, row=(lane>>4)*4+r; apply mask -> -inf
#pragma unroll
  for (int mi = 0; mi < 4; ++mi)
#pragma unroll
    for (int r = 0; r < 4; ++r) {
      int row = erow0 + mi * 16 + r;
      if (row < G_ROWS) {
#pragma unroll
        for (int ni = 0; ni < 4; ++ni) {
          bool on = (mbits >> ((mi * 4 + r) * 4 + ni)) & 1;
          float v = on ? acc[mi][ni][r] * SIM_SCALE : -INFINITY;
          Sim[(size_t)row * T_DIM + ecol0 + ni * 16] = v;
        }
      }
    }
}

// ---------------- ballot-based wave count of keys > tau (wave-uniform result) ----------------
__device__ __forceinline__ int count_above_b(const u32* u, u32 tau) {
  int c = 0;
#pragma unroll
  for (int j = 0; j < 24; ++j) c += (int)__popcll(__ballot(u[j] > tau));
  return c;
}
__device__ __forceinline__ float wave_max_f(float v) {
#pragma unroll
  for (int off = 32; off > 0; off >>= 1) v = fmaxf(v, __shfl_xor(v, off, 64));
  return v;
}

// ---------------- per-row (1 wave/row): float-bisect select, np-replica at boundary,
// emit tIdx/tW only (attn scatter happens post-memset in combine) ----------------
__global__ __launch_bounds__(256) void topk_kernel(const float* __restrict__ Sim,
                                                   const float* __restrict__ tg_dec,
                                                   const float* __restrict__ tf_base,
                                                   int* __restrict__ tIdx, float* __restrict__ tW)
{
  __shared__ u32 cval[4][64];
  __shared__ int cidxs[4][64];
  const int lane = threadIdx.x & 63;
  const int wv   = threadIdx.x >> 6;
  const int g    = blockIdx.x * 4 + wv;
  const float* row = Sim + (size_t)g * T_DIM;

  // --- vector-load row (mask already folded: masked = -inf -> key 0) ---
  u32 u[24];
#pragma unroll
  for (int j = 0; j < 6; ++j) {
    float4 q = *(const float4*)(row + j * 256 + lane * 4);
    float qv[4] = {q.x, q.y, q.z, q.w};
#pragma unroll
    for (int c = 0; c < 4; ++c) {
      u32 b = __float_as_uint(qv[c]);
      u[j * 4 + c] = (b == 0xFF800000u) ? 0u : ((b & 0x80000000u) ? ~b : (b | 0x80000000u));
    }
  }

  // --- float-space bisection: candidate count in [36, 64] ---
  u32 tau = 0u;
  int c_all = count_above_b(u, 0u);
  if (c_all > 64) {
    float flo = -8.f, fhi = 8.f;
    for (int it = 0; it < 24; ++it) {
      float fm = 0.5f * (flo + fhi);
      u32 km = fkey(fm);
      int c = count_above_b(u, km);
      if (c > 64)      flo = fm;
      else if (c < 36) fhi = fm;
      else { tau = km; break; }
    }
    if (tau == 0u) tau = fkey(flo);   // pathological ties only; compaction clamps
  }

  // --- ballot-prefix compaction of candidates into LDS ---
  int base = 0;
#pragma unroll
  for (int j = 0; j < 24; ++j) {
    bool pred = (u[j] > tau);
    u64 bm = __ballot(pred);
    int pos = base + (int)__popcll(bm & ((1ull << lane) - 1ull));
    int idx = (j >> 2) * 256 + lane * 4 + (j & 3);
    if (pred && pos < 64) { cval[wv][pos] = u[j]; cidxs[wv][pos] = idx; }
    base += (int)__popcll(bm);
  }
  const int cnt_eff = (base < 64) ? base : 64;
  __syncthreads();

  u32 myu = 0u; int myidx = 0x7FFFFFFF; float myv = -INFINITY;
  if (lane < cnt_eff) {
    myu = cval[wv][lane]; myidx = cidxs[wv][lane];
    u32 b = (myu & 0x80000000u) ? (myu & 0x7FFFFFFFu) : ~myu;
    myv = __uint_as_float(b);
  }

  // --- rank by (screened value desc, idx asc) ---
  u64 key = ((u64)myu << 32) | (u64)(u32)(~(u32)myidx);
  int rank = 0;
  for (int c = 0; c < cnt_eff; ++c) {
    u64 kc = __shfl(key, c, 64);
    rank += (kc > key) ? 1 : 0;
  }

  // --- contested boundary? np-replica re-sim only within eps of the 31/32 cut ---
  float v31 = wave_max_f((rank == 31) ? myv : -INFINITY);
  float v32 = wave_max_f((rank == 32) ? myv : -INFINITY);
  bool flag = (cnt_eff > TOPK) && (lane < cnt_eff) &&
              (myv >= v32 - BOUND_EPS) && (myv <= v31 + BOUND_EPS);
  if (__ballot(flag) != 0ull) {
    if (flag) {
      // bit-exact np replica: OpenBLAS sgemm sequential-K FMA chain, kc split 384|128,
      // then f32 division by f32(sqrt(512)). Requires strict FP (no fast-math).
      const float* arow_g = tg_dec + (size_t)g * D_DIM;
      const float* brow   = tf_base + (size_t)myidx * D_DIM;
      float s1 = 0.f, s2 = 0.f;
#pragma unroll 8
      for (int k = 0; k < 384; k += 4) {
        float4 av = *(const float4*)(arow_g + k);
        float4 bv = *(const float4*)(brow + k);
        s1 = fmaf(av.x, bv.x, s1); s1 = fmaf(av.y, bv.y, s1);
        s1 = fmaf(av.z, bv.z, s1); s1 = fmaf(av.w, bv.w, s1);
      }
#pragma unroll 8
      for (int k = 384; k < 512; k += 4) {
        float4 av = *(const float4*)(arow_g + k);
        float4 bv = *(const float4*)(brow + k);
        s2 = fmaf(av.x, bv.x, s2); s2 = fmaf(av.y, bv.y, s2);
        s2 = fmaf(av.z, bv.z, s2); s2 = fmaf(av.w, bv.w, s2);
      }
      myv = (s1 + s2) / SQRT_D;
    }
    u32 b2 = __float_as_uint(myv);
    u32 o2 = (b2 & 0x80000000u) ? ~b2 : (b2 | 0x80000000u);
    if (lane >= cnt_eff) o2 = 0u;
    key = ((u64)o2 << 32) | (u64)(u32)(~(u32)myidx);
    rank = 0;
    for (int c = 0; c < cnt_eff; ++c) {
      u64 kc = __shfl(key, c, 64);
      rank += (kc > key) ? 1 : 0;
    }
  }

  // --- weights (m-shift cancels in ratio; 1e-8*Z term dropped: <=1.5e-5 abs) ---
  const bool selme = (lane < cnt_eff) && (rank < TOPK);
  float mx = wave_max_f(selme ? myv : -INFINITY);
  float e = selme ? __expf(myv - mx) : 0.f;
  float E = e;
#pragma unroll
  for (int off = 32; off > 0; off >>= 1) E += __shfl_xor(E, off, 64);
  float rden = (E > 0.f) ? (1.f / E) : 0.f;
  float w = e * rden;

  if (cnt_eff < TOPK && lane >= cnt_eff && lane < TOPK) {   // defensive (never for this input)
    tIdx[(size_t)g * TOPK + lane] = 0; tW[(size_t)g * TOPK + lane] = 0.f;
  }
  if (selme) {
    tIdx[(size_t)g * TOPK + rank] = myidx;
    tW[(size_t)g * TOPK + rank]   = w;
  }
}

// ---------------- out0[b,g] = scale * sum_k w[g,k] * tfT[idx[g,k], b]; also scatter attn ----------------
__global__ __launch_bounds__(256) void combine_kernel(const float* __restrict__ tfT, const int* __restrict__ tIdx,
                                                      const float* __restrict__ tW, const float* __restrict__ scalep,
                                                      float* __restrict__ out0, float* __restrict__ attn)
{
  __shared__ int   sIdx[16 * 32];
  __shared__ float sW[16 * 32];
  const int tid = threadIdx.x;
  const int g0 = blockIdx.x * 16;
  for (int i = tid; i < 512; i += 256) {
    sIdx[i] = tIdx[(size_t)g0 * 32 + i];
    sW[i]   = tW[(size_t)g0 * 32 + i];
  }
  __syncthreads();
  // scatter sparse attn (region was memset to 0 just before this kernel)
  for (int i = tid; i < 512; i += 256) {
    attn[(size_t)(g0 + (i >> 5)) * T_DIM + sIdx[i]] = sW[i];
  }
  const float scale = scalep[0];
  float acc[16];
#pragma unroll
  for (int gi = 0; gi < 16; ++gi) acc[gi] = 0.f;
#pragma unroll 4
  for (int gi = 0; gi < 16; ++gi) {
    float a = 0.f;
#pragma unroll
    for (int k = 0; k < 32; ++k) {
      float w = sW[gi * 32 + k];
      int t   = sIdx[gi * 32 + k];
      a += w * tfT[(size_t)t * B_DIM + tid];
    }
    acc[gi] = a;
  }
  float* dst = out0 + (size_t)tid * G_ROWS + g0;
#pragma unroll
  for (int q = 0; q < 4; ++q) {
    float4 o = make_float4(scale * acc[4*q], scale * acc[4*q+1], scale * acc[4*q+2], scale * acc[4*q+3]);
    *(float4*)(dst + 4 * q) = o;
  }
}

extern "C" void kernel_launch(void* const* d_in, const int* in_sizes, int n_in,
                              void* d_out, int out_size, void* d_ws, size_t ws_size,
                              hipStream_t stream)
{
  const float* tg_dec     = (const float*)d_in[0];
  const float* tf_base    = (const float*)d_in[1];
  const float* tf_expr    = (const float*)d_in[2];
  const int*   motif_mask = (const int*)d_in[3];
  const float* scale      = (const float*)d_in[4];

  float* out0 = (float*)d_out;                           // [B, G]
  float* attn = out0 + (size_t)B_DIM * G_ROWS;           // [G, T] — Sim scratch, then zero+scatter

  char* ws = (char*)d_ws;
  u16*   Ah  = (u16*)(ws);                               // G_PAD*512 bf16
  u16*   Al  = (u16*)(ws + 20578304);
  u16*   Bh  = (u16*)(ws + 41156608);                    // 1536*512 bf16
  u16*   Bl  = (u16*)(ws + 42729472);
  float* tfT = (float*)(ws + 44302336);                  // [T, B] f32
  int*   tIdx = (int*)(ws + 45875200);                   // [G, 32]
  float* tW   = (float*)(ws + 48435200);                 // [G, 32]

  conv_split<<<10048, 256, 0, stream>>>(tg_dec, Ah, Al, G_ROWS);
  conv_split<<<768,   256, 0, stream>>>(tf_base, Bh, Bl, T_DIM);
  transpose_tf<<<dim3(48, 8), dim3(32, 8), 0, stream>>>(tf_expr, tfT);
  gemm_split<<<dim3(12, 157), 256, 0, stream>>>(Ah, Al, Bh, Bl, motif_mask, attn);
  topk_kernel<<<5000, 256, 0, stream>>>(attn, tg_dec, tf_base, tIdx, tW);
  hipMemsetAsync(attn, 0, (size_t)G_ROWS * T_DIM * sizeof(float), stream);
  combine_kernel<<<1250, 256, 0, stream>>>(tfT, tIdx, tW, scale, out0, attn);
}

// Round 6
// 588.967 us; speedup vs baseline: 1.0934x; 1.0934x over previous
//
#include <hip/hip_runtime.h>
#include <cstdint>

typedef unsigned short u16;
typedef unsigned int   u32;
typedef unsigned long long u64;

#define G_ROWS 20000
#define G_PAD  20096      // 157 * 128
#define T_DIM  1536
#define D_DIM  512
#define B_DIM  256
#define TOPK   32
#define SIM_SCALE 0.04419417382415922f   // 1/sqrt(512), screening only
#define SQRT_D    22.62741699796952f     // f32(math.sqrt(512)) — np divides by this
#define BOUND_EPS 2.0e-4f                // screen-vs-np noise is ~5e-6; 40x margin

typedef __bf16 bf16x8 __attribute__((ext_vector_type(8)));
typedef float  f32x4  __attribute__((ext_vector_type(4)));

__device__ __forceinline__ u16 f2bf(float f) {
  u32 u = __float_as_uint(f);
  u += 0x7fffu + ((u >> 16) & 1u);   // RNE
  return (u16)(u >> 16);
}
__device__ __forceinline__ float bf2f(u16 h) {
  return __uint_as_float(((u32)h) << 16);
}

// ---------------- split-conversion: f32 -> (bf16 hi, bf16 lo) ----------------
__global__ __launch_bounds__(256) void conv_split(const float* __restrict__ src,
                                                  u16* __restrict__ hi, u16* __restrict__ lo,
                                                  int valid_rows)
{
  size_t i = ((size_t)blockIdx.x * 256 + threadIdx.x) * 4;
  int row = (int)(i >> 9);
  float4 a = make_float4(0.f, 0.f, 0.f, 0.f);
  if (row < valid_rows) a = *(const float4*)(src + i);
  float v[4] = {a.x, a.y, a.z, a.w};
  u16 h[4], l[4];
#pragma unroll
  for (int c = 0; c < 4; ++c) {
    h[c] = f2bf(v[c]);
    l[c] = f2bf(v[c] - bf2f(h[c]));
  }
  *(uint2*)(hi + i) = make_uint2((u32)h[0] | ((u32)h[1] << 16), (u32)h[2] | ((u32)h[3] << 16));
  *(uint2*)(lo + i) = make_uint2((u32)l[0] | ((u32)l[1] << 16), (u32)l[2] | ((u32)l[3] << 16));
}

// ---------------- tf_expr [B,T] -> tfT [T,B] ----------------
__global__ __launch_bounds__(256) void transpose_tf(const float* __restrict__ in, float* __restrict__ out)
{
  __shared__ float tile[32][33];
  int x = threadIdx.x, y = threadIdx.y;
  int bt = blockIdx.x * 32;
  int bb = blockIdx.y * 32;
#pragma unroll
  for (int i = 0; i < 32; i += 8) tile[y + i][x] = in[(size_t)(bb + y + i) * T_DIM + bt + x];
  __syncthreads();
#pragma unroll
  for (int i = 0; i < 32; i += 8) out[(size_t)(bt + y + i) * B_DIM + bb + x] = tile[x][y + i];
}

// ---------------- async global -> LDS, 16B/lane ----------------
__device__ __forceinline__ void gl16(const u16* g, u16* l) {
  __builtin_amdgcn_global_load_lds((__attribute__((address_space(1))) void*)(void*)g,
                                   (__attribute__((address_space(3))) void*)l, 16, 0, 0);
}

// ---------------- screening GEMM: C ~= (Ah+Al)(Bh+Bl)^T via 3 bf16 MFMA terms ----------------
__global__ __launch_bounds__(256) void gemm_split(const u16* __restrict__ Ah, const u16* __restrict__ Al,
                                                  const u16* __restrict__ Bh, const u16* __restrict__ Bl,
                                                  float* __restrict__ Sim)
{
  __shared__ u16 sm[16384];
  const int tid  = threadIdx.x;
  const int lane = tid & 63;
  const int wv   = tid >> 6;
  const int m0 = blockIdx.y * 128;
  const int n0 = blockIdx.x * 128;

  f32x4 zero4 = {0.f, 0.f, 0.f, 0.f};
  f32x4 acc[4][4];
#pragma unroll
  for (int i = 0; i < 4; ++i)
#pragma unroll
    for (int j = 0; j < 4; ++j) acc[i][j] = zero4;

  const int r0 = (wv << 4) + (lane >> 2);
  const int c0 = (lane & 3) << 3;
  const size_t aoff = (size_t)(m0 + r0) * 512 + c0;
  const size_t boff = (size_t)(n0 + r0) * 512 + c0;
  u16* lw = sm + (wv << 9);

  const int arow = ((wv >> 1) << 6) + (lane & 15);
  const int brow = ((wv & 1) << 6) + (lane & 15);
  const int kf   = (lane >> 4) << 3;

  for (int kt = 0; kt < 16; ++kt) {
    const int k0 = kt << 5;
    __syncthreads();
    gl16(Ah + aoff + k0,            lw);
    gl16(Ah + aoff + k0 + 64 * 512, lw + 2048);
    gl16(Al + aoff + k0,            lw + 4096);
    gl16(Al + aoff + k0 + 64 * 512, lw + 6144);
    gl16(Bh + boff + k0,            lw + 8192);
    gl16(Bh + boff + k0 + 64 * 512, lw + 10240);
    gl16(Bl + boff + k0,            lw + 12288);
    gl16(Bl + boff + k0 + 64 * 512, lw + 14336);
    __syncthreads();

    bf16x8 aH[4], aL[4], bH[4], bL[4];
#pragma unroll
    for (int mi = 0; mi < 4; ++mi) {
      aH[mi] = *(const bf16x8*)(sm +        (arow + mi * 16) * 32 + kf);
      aL[mi] = *(const bf16x8*)(sm + 4096 + (arow + mi * 16) * 32 + kf);
    }
#pragma unroll
    for (int ni = 0; ni < 4; ++ni) {
      bH[ni] = *(const bf16x8*)(sm + 8192  + (brow + ni * 16) * 32 + kf);
      bL[ni] = *(const bf16x8*)(sm + 12288 + (brow + ni * 16) * 32 + kf);
    }
#pragma unroll
    for (int mi = 0; mi < 4; ++mi)
#pragma unroll
      for (int ni = 0; ni < 4; ++ni) {
        acc[mi][ni] = __builtin_amdgcn_mfma_f32_16x16x32_bf16(aH[mi], bH[ni], acc[mi][ni], 0, 0, 0);
        acc[mi][ni] = __builtin_amdgcn_mfma_f32_16x16x32_bf16(aH[mi], bL[ni], acc[mi][ni], 0, 0, 0);
        acc[mi][ni] = __builtin_amdgcn_mfma_f32_16x16x32_bf16(aL[mi], bH[ni], acc[mi][ni], 0, 0, 0);
      }
  }

  const int erow0 = m0 + ((wv >> 1) << 6) + ((lane >> 4) << 2);
  const int ecol0 = n0 + ((wv & 1) << 6) + (lane & 15);
#pragma unroll
  for (int mi = 0; mi < 4; ++mi)
#pragma unroll
    for (int r = 0; r < 4; ++r) {
      int row = erow0 + mi * 16 + r;
      if (row < G_ROWS) {
#pragma unroll
        for (int ni = 0; ni < 4; ++ni)
          Sim[(size_t)row * T_DIM + ecol0 + ni * 16] = acc[mi][ni][r] * SIM_SCALE;
      }
    }
}

// ---------------- helpers ----------------
__device__ __forceinline__ float wave_max_f(float v) {
#pragma unroll
  for (int off = 32; off > 0; off >>= 1) v = fmaxf(v, __shfl_xor(v, off, 64));
  return v;
}
__device__ __forceinline__ int count_ge(const float* v, float tau) {
  int c = 0;
#pragma unroll
  for (int j = 0; j < 24; ++j) c += (int)__popcll(__ballot(v[j] >= tau));
  return c;
}

// ---------------- per-row (1 wave/row, NO inter-wave barriers): histogram threshold,
// compaction, np-replica at contested boundary, in-place dense attn write ----------------
__global__ __launch_bounds__(256) void topk_kernel(float* __restrict__ Sim, const int* __restrict__ mask,
                                                   const float* __restrict__ tg_dec,
                                                   const float* __restrict__ tf_base,
                                                   int* __restrict__ tIdx, float* __restrict__ tW)
{
  __shared__ float srow[4][T_DIM];   // 24 KB, wave-private slices
  __shared__ u32   hist[4][64];      // 1 KB
  __shared__ u32   cval[4][64];
  __shared__ int   cidxs[4][64];
  const int lane = threadIdx.x & 63;
  const int wv   = threadIdx.x >> 6;
  const int g    = blockIdx.x * 4 + wv;
  float* row = Sim + (size_t)g * T_DIM;
  const int* mrow = mask + (size_t)g * T_DIM;

  // --- vectorized load of sim + mask; apply mask -> -inf ---
  float v[24];
#pragma unroll
  for (int j = 0; j < 6; ++j) {
    float4 q = *(const float4*)(row + j * 256 + lane * 4);
    int4  mq = *(const int4*)(mrow + j * 256 + lane * 4);
    v[j * 4 + 0] = mq.x ? q.x : -INFINITY;
    v[j * 4 + 1] = mq.y ? q.y : -INFINITY;
    v[j * 4 + 2] = mq.z ? q.z : -INFINITY;
    v[j * 4 + 3] = mq.w ? q.w : -INFINITY;
  }

  // --- per-wave 64-bin histogram over [-4,4); one pass, no serial bisection ---
  hist[wv][lane] = 0;
  __threadfence_block();
#pragma unroll
  for (int j = 0; j < 24; ++j) {
    if (v[j] != -INFINITY) {
      int b = (int)((v[j] + 4.f) * 8.f);
      b = (b < 0) ? 0 : ((b > 63) ? 63 : b);
      atomicAdd(&hist[wv][b], 1u);
    }
  }
  __threadfence_block();
  int D = (int)hist[wv][lane];
  // suffix-scan: D_lane = sum of hist[lane..63]
#pragma unroll
  for (int off = 1; off < 64; off <<= 1) {
    int t = __shfl_down(D, off, 64);
    if (lane + off < 64) D += t;
  }
  // largest bin b* with >=36 values at or above its lower edge
  u64 bm = __ballot(D >= 36);
  int bstar = 63 - (int)__builtin_clzll(bm);   // bm != 0: valid count ~768
  int cnt = __shfl(D, bstar, 64);
  float tau = (float)bstar * 0.125f - 4.f;     // exact edge (multiples of 1/8)

  if (cnt > 64) {                               // fat-bin fallback (~never for N(0,1) data)
    float elo = tau, ehi = tau + 0.125f;
    for (int it = 0; it < 16; ++it) {
      float mid = 0.5f * (elo + ehi);
      int cm = count_ge(v, mid);
      if (cm > 64) { elo = mid; cnt = cm; }
      else if (cm < 36) ehi = mid;
      else { tau = mid; cnt = cm; break; }
    }
    if (cnt > 64) tau = elo;                    // compaction clamps (ties, prob ~0)
  }

  // --- ballot-prefix compaction into wave-private LDS ---
  int base = 0;
#pragma unroll
  for (int j = 0; j < 24; ++j) {
    bool pred = (v[j] >= tau);
    u64 bmc = __ballot(pred);
    int pos = base + (int)__popcll(bmc & ((1ull << lane) - 1ull));
    int idx = (j >> 2) * 256 + lane * 4 + (j & 3);
    if (pred && pos < 64) { cval[wv][pos] = __float_as_uint(v[j]); cidxs[wv][pos] = idx; }
    base += (int)__popcll(bmc);
  }
  const int cnt_eff = (base < 64) ? base : 64;
  __threadfence_block();

  int myidx = 0x7FFFFFFF; float myv = -INFINITY;
  if (lane < cnt_eff) {
    myv = __uint_as_float(cval[wv][lane]);
    myidx = cidxs[wv][lane];
  }

  // --- rank by (value desc, idx asc) ---
  u32 mku = (__float_as_uint(myv) & 0x80000000u) ? ~__float_as_uint(myv)
                                                 : (__float_as_uint(myv) | 0x80000000u);
  if (lane >= cnt_eff) mku = 0u;
  u64 key = ((u64)mku << 32) | (u64)(u32)(~(u32)myidx);
  int rank = 0;
  for (int c = 0; c < cnt_eff; ++c) {
    u64 kc = __shfl(key, c, 64);
    rank += (kc > key) ? 1 : 0;
  }

  // --- contested boundary? np-replica re-sim only within eps of the 31/32 cut ---
  float v31 = wave_max_f((rank == 31) ? myv : -INFINITY);
  float v32 = wave_max_f((rank == 32) ? myv : -INFINITY);
  bool flag = (cnt_eff > TOPK) && (lane < cnt_eff) &&
              (myv >= v32 - BOUND_EPS) && (myv <= v31 + BOUND_EPS);
  if (__ballot(flag) != 0ull) {
    if (flag) {
      // bit-exact np replica: OpenBLAS sgemm sequential-K FMA chain, kc split 384|128,
      // then f32 division by f32(sqrt(512)). Requires strict FP (no fast-math).
      const float* arow_g = tg_dec + (size_t)g * D_DIM;
      const float* brow   = tf_base + (size_t)myidx * D_DIM;
      float s1 = 0.f, s2 = 0.f;
#pragma unroll 8
      for (int k = 0; k < 384; k += 4) {
        float4 av = *(const float4*)(arow_g + k);
        float4 bv = *(const float4*)(brow + k);
        s1 = fmaf(av.x, bv.x, s1); s1 = fmaf(av.y, bv.y, s1);
        s1 = fmaf(av.z, bv.z, s1); s1 = fmaf(av.w, bv.w, s1);
      }
#pragma unroll 8
      for (int k = 384; k < 512; k += 4) {
        float4 av = *(const float4*)(arow_g + k);
        float4 bv = *(const float4*)(brow + k);
        s2 = fmaf(av.x, bv.x, s2); s2 = fmaf(av.y, bv.y, s2);
        s2 = fmaf(av.z, bv.z, s2); s2 = fmaf(av.w, bv.w, s2);
      }
      myv = (s1 + s2) / SQRT_D;
    }
    u32 b2 = __float_as_uint(myv);
    u32 o2 = (b2 & 0x80000000u) ? ~b2 : (b2 | 0x80000000u);
    if (lane >= cnt_eff) o2 = 0u;
    key = ((u64)o2 << 32) | (u64)(u32)(~(u32)myidx);
    rank = 0;
    for (int c = 0; c < cnt_eff; ++c) {
      u64 kc = __shfl(key, c, 64);
      rank += (kc > key) ? 1 : 0;
    }
  }

  // --- weights (m-shift cancels in ratio; 1e-8*Z term dropped: <=1.5e-5 abs) ---
  const bool selme = (lane < cnt_eff) && (rank < TOPK);
  float mx = wave_max_f(selme ? myv : -INFINITY);
  float e = selme ? __expf(myv - mx) : 0.f;
  float E = e;
#pragma unroll
  for (int off = 32; off > 0; off >>= 1) E += __shfl_xor(E, off, 64);
  float rden = (E > 0.f) ? (1.f / E) : 0.f;
  float w = e * rden;

  // --- dense in-place attn write via wave-private LDS (zero -> scatter -> writeback) ---
  float* sr = srow[wv];
  const float4 z4 = make_float4(0.f, 0.f, 0.f, 0.f);
#pragma unroll
  for (int j = 0; j < 6; ++j) *(float4*)(sr + j * 256 + lane * 4) = z4;
  __threadfence_block();
  if (selme) sr[myidx] = w;
  __threadfence_block();
#pragma unroll
  for (int j = 0; j < 6; ++j) *(float4*)(row + j * 256 + lane * 4) = *(const float4*)(sr + j * 256 + lane * 4);

  if (cnt_eff < TOPK && lane >= cnt_eff && lane < TOPK) {   // defensive (never for this input)
    tIdx[(size_t)g * TOPK + lane] = 0; tW[(size_t)g * TOPK + lane] = 0.f;
  }
  if (selme) {
    tIdx[(size_t)g * TOPK + rank] = myidx;
    tW[(size_t)g * TOPK + rank]   = w;
  }
}

// ---------------- out0[b,g] = scale * sum_k w[g,k] * tfT[idx[g,k], b] ----------------
__global__ __launch_bounds__(256) void combine_kernel(const float* __restrict__ tfT, const int* __restrict__ tIdx,
                                                      const float* __restrict__ tW, const float* __restrict__ scalep,
                                                      float* __restrict__ out0)
{
  __shared__ int   sIdx[16 * 32];
  __shared__ float sW[16 * 32];
  const int tid = threadIdx.x;
  const int g0 = blockIdx.x * 16;
  for (int i = tid; i < 512; i += 256) {
    sIdx[i] = tIdx[(size_t)g0 * 32 + i];
    sW[i]   = tW[(size_t)g0 * 32 + i];
  }
  __syncthreads();
  const float scale = scalep[0];
  float acc[16];
#pragma unroll
  for (int gi = 0; gi < 16; ++gi) acc[gi] = 0.f;
#pragma unroll 4
  for (int gi = 0; gi < 16; ++gi) {
    float a = 0.f;
#pragma unroll
    for (int k = 0; k < 32; ++k) {
      float w = sW[gi * 32 + k];
      int t   = sIdx[gi * 32 + k];
      a += w * tfT[(size_t)t * B_DIM + tid];
    }
    acc[gi] = a;
  }
  float* dst = out0 + (size_t)tid * G_ROWS + g0;
#pragma unroll
  for (int q = 0; q < 4; ++q) {
    float4 o = make_float4(scale * acc[4*q], scale * acc[4*q+1], scale * acc[4*q+2], scale * acc[4*q+3]);
    *(float4*)(dst + 4 * q) = o;
  }
}

extern "C" void kernel_launch(void* const* d_in, const int* in_sizes, int n_in,
                              void* d_out, int out_size, void* d_ws, size_t ws_size,
                              hipStream_t stream)
{
  const float* tg_dec     = (const float*)d_in[0];
  const float* tf_base    = (const float*)d_in[1];
  const float* tf_expr    = (const float*)d_in[2];
  const int*   motif_mask = (const int*)d_in[3];
  const float* scale      = (const float*)d_in[4];

  float* out0 = (float*)d_out;                           // [B, G]
  float* attn = out0 + (size_t)B_DIM * G_ROWS;           // [G, T] — Sim scratch, overwritten in place

  char* ws = (char*)d_ws;
  u16*   Ah  = (u16*)(ws);                               // G_PAD*512 bf16
  u16*   Al  = (u16*)(ws + 20578304);
  u16*   Bh  = (u16*)(ws + 41156608);                    // 1536*512 bf16
  u16*   Bl  = (u16*)(ws + 42729472);
  float* tfT = (float*)(ws + 44302336);                  // [T, B] f32
  int*   tIdx = (int*)(ws + 45875200);                   // [G, 32]
  float* tW   = (float*)(ws + 48435200);                 // [G, 32]

  conv_split<<<10048, 256, 0, stream>>>(tg_dec, Ah, Al, G_ROWS);
  conv_split<<<768,   256, 0, stream>>>(tf_base, Bh, Bl, T_DIM);
  transpose_tf<<<dim3(48, 8), dim3(32, 8), 0, stream>>>(tf_expr, tfT);
  gemm_split<<<dim3(12, 157), 256, 0, stream>>>(Ah, Al, Bh, Bl, attn);
  topk_kernel<<<5000, 256, 0, stream>>>(attn, motif_mask, tg_dec, tf_base, tIdx, tW);
  combine_kernel<<<1250, 256, 0, stream>>>(tfT, tIdx, tW, scale, out0);
}